// Round 7
// baseline (355.353 us; speedup 1.0000x reference)
//
#include <hip/hip_runtime.h>
#include <stdint.h>

#define BB 4
#define LL 4096
#define DD 64

typedef __attribute__((ext_vector_type(8))) short bf16x8;
typedef __attribute__((ext_vector_type(4))) float f32x4;

static __device__ __forceinline__ unsigned short f2bf(float x) {
    // round-to-nearest-even f32 -> bf16
    unsigned int u = __builtin_bit_cast(unsigned int, x);
    u += 0x7fffu + ((u >> 16) & 1u);
    return (unsigned short)(u >> 16);
}

// ---------------------------------------------------------------------------
// Kernel 1: convert q,k (f32) -> bf16 in ws. k-blocks also emit deterministic
// per-block column partial sums (32 rows x 64 cols per block).
// ---------------------------------------------------------------------------
__global__ __launch_bounds__(256) void convert_kernel(
    const float* __restrict__ q, const float* __restrict__ k,
    unsigned short* __restrict__ qbf, unsigned short* __restrict__ kbf,
    float* __restrict__ part)
{
    const int NBQ = (BB * LL * DD) / 2048;   // 512
    int bid = blockIdx.x;
    bool is_k = bid >= NBQ;
    const float* src = is_k ? k : q;
    unsigned short* dst = is_k ? kbf : qbf;
    int cb = is_k ? (bid - NBQ) : bid;
    int tid = threadIdx.x;

    size_t idx0 = (size_t)cb * 2048 + (size_t)tid * 8;
    float4 f0 = *(const float4*)(src + idx0);
    float4 f1 = *(const float4*)(src + idx0 + 4);
    float f[8] = {f0.x, f0.y, f0.z, f0.w, f1.x, f1.y, f1.z, f1.w};

    unsigned short u[8];
    #pragma unroll
    for (int e = 0; e < 8; e++) u[e] = f2bf(f[e]);
    uint4 pk;
    pk.x = (unsigned)u[0] | ((unsigned)u[1] << 16);
    pk.y = (unsigned)u[2] | ((unsigned)u[3] << 16);
    pk.z = (unsigned)u[4] | ((unsigned)u[5] << 16);
    pk.w = (unsigned)u[6] | ((unsigned)u[7] << 16);
    *(uint4*)(dst + idx0) = pk;

    if (is_k) {
        __shared__ float red[256][8];
        #pragma unroll
        for (int e = 0; e < 8; e++) red[tid][e] = f[e];
        __syncthreads();
        if (tid < 64) {
            int g = tid >> 3, e = tid & 7;
            float s = 0.f;
            #pragma unroll
            for (int r = 0; r < 32; r++) s += red[r * 8 + g][e];
            part[(size_t)cb * 64 + tid] = s;
        }
    }
}

// ---------------------------------------------------------------------------
// Kernel 2: output[b,i,r] = sum_t q[b,i,t]*coef[b,t]*v[b,t,r]
// ---------------------------------------------------------------------------
__global__ __launch_bounds__(256) void out_kernel(
    const float* __restrict__ q, const float* __restrict__ v,
    const float* __restrict__ vec, const float* __restrict__ part,
    float* __restrict__ out)
{
    __shared__ float csh[64];
    __shared__ float Vl[64][65];
    __shared__ float qs[32][65];

    int bid = blockIdx.x;
    int b   = bid >> 7;
    int i0  = (bid & 127) << 5;
    int tid = threadIdx.x;

    if (tid < 64) {
        const float* pp = part + (size_t)b * 128 * 64 + tid;
        float s = 0.f;
        #pragma unroll 8
        for (int c = 0; c < 128; c++) s += pp[c * 64];
        csh[tid] = 0.0625f * (vec[tid] + vec[64 + tid]) * s;
    }
    {
        const float* vb = v + (size_t)b * LL * DD;
        #pragma unroll
        for (int it = 0; it < 4; it++) {
            int idx4 = it * 256 + tid;
            int t  = idx4 >> 4;
            int r4 = (idx4 & 15) << 2;
            float4 w = *(const float4*)(vb + (size_t)idx4 * 4);
            Vl[t][r4 + 0] = w.x; Vl[t][r4 + 1] = w.y;
            Vl[t][r4 + 2] = w.z; Vl[t][r4 + 3] = w.w;
        }
    }
    __syncthreads();
    {
        const float* qb = q + (size_t)b * LL * DD;
        int row = tid >> 3;
        int t0  = (tid & 7) << 3;
        const float* src = qb + (size_t)(i0 + row) * DD + t0;
        float4 a0 = *(const float4*)(src);
        float4 a1 = *(const float4*)(src + 4);
        float fa[8] = {a0.x,a0.y,a0.z,a0.w,a1.x,a1.y,a1.z,a1.w};
        #pragma unroll
        for (int e = 0; e < 8; e++) qs[row][t0 + e] = fa[e] * csh[t0 + e];
    }
    __syncthreads();

    int ii = tid >> 3;
    int g  = tid & 7;
    float acc[8] = {0,0,0,0,0,0,0,0};
    #pragma unroll 8
    for (int t = 0; t < 64; t++) {
        float qv = qs[ii][t];
        #pragma unroll
        for (int j = 0; j < 8; j++) acc[j] += qv * Vl[t][g * 8 + j];
    }
    float* op = out + (size_t)b * LL * DD + (size_t)(i0 + ii) * DD + g * 8;
    float4 s0 = {acc[0], acc[1], acc[2], acc[3]};
    float4 s1 = {acc[4], acc[5], acc[6], acc[7]};
    *(float4*)(op)     = s0;
    *(float4*)(op + 4) = s1;
}

// ---------------------------------------------------------------------------
// Kernel 3 — DIAGNOSTIC BUILD: r6 streaming attn, but the j-sweep is run
// 3 IDENTICAL passes (idempotent stores, same output) so this dispatch
// exceeds the ~160 µs fill dispatches and lands in the rocprof top-5,
// exposing its FETCH/WRITE/MfmaUtil/VALUBusy/Occupancy counters.
// A memory-clobber per pass prevents LICM from hoisting loads/MFMA.
// ---------------------------------------------------------------------------
__global__ __launch_bounds__(512, 4) void attn_kernel(
    const unsigned short* __restrict__ qbf,
    const unsigned short* __restrict__ kbf,
    float* __restrict__ attn)
{
    int bid = blockIdx.x;
    int swz = (bid & 7) * 64 + (bid >> 3);
    int b   = swz >> 7;
    int ti  = swz & 127;
    int i0  = ti * 32;

    int tid  = threadIdx.x;
    int w    = tid >> 6;
    int lane = tid & 63;
    int lr = lane & 15;
    int g  = lane >> 4;
    int lk = g * 8;
    int jb = g * 4;

    const unsigned short* qb = qbf + (size_t)b * LL * DD;
    const unsigned short* kb = kbf + (size_t)b * LL * DD;
    float* ab = attn + (size_t)b * LL * LL;

    bf16x8 qf[2][2];
    #pragma unroll
    for (int m = 0; m < 2; m++)
        #pragma unroll
        for (int kk = 0; kk < 2; kk++)
            qf[m][kk] = *(const bf16x8*)(
                qb + (size_t)(i0 + m * 16 + lr) * DD + kk * 32 + lk);

    #pragma unroll 1
    for (int pass = 0; pass < 3; ++pass) {
        // defeat LICM: force k reloads + MFMA re-execution each pass
        asm volatile("" ::: "memory");

        #pragma unroll
        for (int tj = 0; tj < 8; tj++) {
            int j0 = tj * 512 + w * 64;

            bf16x8 kf[4][2];
            #pragma unroll
            for (int n = 0; n < 4; n++)
                #pragma unroll
                for (int kk = 0; kk < 2; kk++)
                    kf[n][kk] = *(const bf16x8*)(
                        kb + (size_t)(j0 + n * 16 + lr) * DD + kk * 32 + lk);

            f32x4 acc[2][4];
            #pragma unroll
            for (int m = 0; m < 2; m++)
                #pragma unroll
                for (int n = 0; n < 4; n++)
                    acc[m][n] = (f32x4){0.f, 0.f, 0.f, 0.f};

            #pragma unroll
            for (int kk = 0; kk < 2; kk++)
                #pragma unroll
                for (int m = 0; m < 2; m++)
                    #pragma unroll
                    for (int n = 0; n < 4; n++)
                        acc[m][n] = __builtin_amdgcn_mfma_f32_16x16x32_bf16(
                            kf[n][kk], qf[m][kk], acc[m][n], 0, 0, 0);

            #pragma unroll
            for (int m = 0; m < 2; m++) {
                size_t roff = (size_t)(i0 + m * 16 + lr) * LL;
                #pragma unroll
                for (int n = 0; n < 4; n++)
                    *(f32x4*)(ab + roff + j0 + n * 16 + jb) = acc[m][n];
            }
        }
    }
}

extern "C" void kernel_launch(void* const* d_in, const int* in_sizes, int n_in,
                              void* d_out, int out_size, void* d_ws, size_t ws_size,
                              hipStream_t stream) {
    const float* q   = (const float*)d_in[0];
    const float* k   = (const float*)d_in[1];
    const float* v   = (const float*)d_in[2];
    const float* vec = (const float*)d_in[3];

    float* out  = (float*)d_out;                          // [4,4096,64]
    float* attn = out + (size_t)BB * LL * DD;             // [4,4096,4096]

    unsigned short* qbf = (unsigned short*)d_ws;          // 2 MB
    unsigned short* kbf = qbf + (size_t)BB * LL * DD;     // 2 MB
    float* part = (float*)(kbf + (size_t)BB * LL * DD);   // 512*64 f32 = 128 KB

    convert_kernel<<<1024, 256, 0, stream>>>(q, k, qbf, kbf, part);
    out_kernel<<<512, 256, 0, stream>>>(q, v, vec, part, out);
    attn_kernel<<<512, 512, 0, stream>>>(qbf, kbf, attn);
}

// Round 8
// 76.857 us; speedup vs baseline: 4.6235x; 4.6235x over previous
//
#include <hip/hip_runtime.h>
#include <stdint.h>

#define BB 4
#define LL 4096
#define DD 64

typedef __attribute__((ext_vector_type(8))) short bf16x8;
typedef __attribute__((ext_vector_type(4))) float f32x4;

static __device__ __forceinline__ unsigned short f2bf(float x) {
    // round-to-nearest-even f32 -> bf16
    unsigned int u = __builtin_bit_cast(unsigned int, x);
    u += 0x7fffu + ((u >> 16) & 1u);
    return (unsigned short)(u >> 16);
}

// ---------------------------------------------------------------------------
// Kernel 1: convert q,k (f32) -> bf16 in ws. k-blocks also emit deterministic
// per-block column partial sums (32 rows x 64 cols per block).
// ---------------------------------------------------------------------------
__global__ __launch_bounds__(256) void convert_kernel(
    const float* __restrict__ q, const float* __restrict__ k,
    unsigned short* __restrict__ qbf, unsigned short* __restrict__ kbf,
    float* __restrict__ part)
{
    const int NBQ = (BB * LL * DD) / 2048;   // 512
    int bid = blockIdx.x;
    bool is_k = bid >= NBQ;
    const float* src = is_k ? k : q;
    unsigned short* dst = is_k ? kbf : qbf;
    int cb = is_k ? (bid - NBQ) : bid;
    int tid = threadIdx.x;

    size_t idx0 = (size_t)cb * 2048 + (size_t)tid * 8;
    float4 f0 = *(const float4*)(src + idx0);
    float4 f1 = *(const float4*)(src + idx0 + 4);
    float f[8] = {f0.x, f0.y, f0.z, f0.w, f1.x, f1.y, f1.z, f1.w};

    unsigned short u[8];
    #pragma unroll
    for (int e = 0; e < 8; e++) u[e] = f2bf(f[e]);
    uint4 pk;
    pk.x = (unsigned)u[0] | ((unsigned)u[1] << 16);
    pk.y = (unsigned)u[2] | ((unsigned)u[3] << 16);
    pk.z = (unsigned)u[4] | ((unsigned)u[5] << 16);
    pk.w = (unsigned)u[6] | ((unsigned)u[7] << 16);
    *(uint4*)(dst + idx0) = pk;

    if (is_k) {
        __shared__ float red[256][8];
        #pragma unroll
        for (int e = 0; e < 8; e++) red[tid][e] = f[e];
        __syncthreads();
        if (tid < 64) {
            int g = tid >> 3, e = tid & 7;
            float s = 0.f;
            #pragma unroll
            for (int r = 0; r < 32; r++) s += red[r * 8 + g][e];
            part[(size_t)cb * 64 + tid] = s;
        }
    }
}

// ---------------------------------------------------------------------------
// Kernel 2: output[b,i,r] = sum_t q[b,i,t]*coef[b,t]*v[b,t,r]
// ---------------------------------------------------------------------------
__global__ __launch_bounds__(256) void out_kernel(
    const float* __restrict__ q, const float* __restrict__ v,
    const float* __restrict__ vec, const float* __restrict__ part,
    float* __restrict__ out)
{
    __shared__ float csh[64];
    __shared__ float Vl[64][65];
    __shared__ float qs[32][65];

    int bid = blockIdx.x;
    int b   = bid >> 7;
    int i0  = (bid & 127) << 5;
    int tid = threadIdx.x;

    if (tid < 64) {
        const float* pp = part + (size_t)b * 128 * 64 + tid;
        float s = 0.f;
        #pragma unroll 8
        for (int c = 0; c < 128; c++) s += pp[c * 64];
        csh[tid] = 0.0625f * (vec[tid] + vec[64 + tid]) * s;
    }
    {
        const float* vb = v + (size_t)b * LL * DD;
        #pragma unroll
        for (int it = 0; it < 4; it++) {
            int idx4 = it * 256 + tid;
            int t  = idx4 >> 4;
            int r4 = (idx4 & 15) << 2;
            float4 w = *(const float4*)(vb + (size_t)idx4 * 4);
            Vl[t][r4 + 0] = w.x; Vl[t][r4 + 1] = w.y;
            Vl[t][r4 + 2] = w.z; Vl[t][r4 + 3] = w.w;
        }
    }
    __syncthreads();
    {
        const float* qb = q + (size_t)b * LL * DD;
        int row = tid >> 3;
        int t0  = (tid & 7) << 3;
        const float* src = qb + (size_t)(i0 + row) * DD + t0;
        float4 a0 = *(const float4*)(src);
        float4 a1 = *(const float4*)(src + 4);
        float fa[8] = {a0.x,a0.y,a0.z,a0.w,a1.x,a1.y,a1.z,a1.w};
        #pragma unroll
        for (int e = 0; e < 8; e++) qs[row][t0 + e] = fa[e] * csh[t0 + e];
    }
    __syncthreads();

    int ii = tid >> 3;
    int g  = tid & 7;
    float acc[8] = {0,0,0,0,0,0,0,0};
    #pragma unroll 8
    for (int t = 0; t < 64; t++) {
        float qv = qs[ii][t];
        #pragma unroll
        for (int j = 0; j < 8; j++) acc[j] += qv * Vl[t][g * 8 + j];
    }
    float* op = out + (size_t)b * LL * DD + (size_t)(i0 + ii) * DD + g * 8;
    float4 s0 = {acc[0], acc[1], acc[2], acc[3]};
    float4 s1 = {acc[4], acc[5], acc[6], acc[7]};
    *(float4*)(op)     = s0;
    *(float4*)(op + 4) = s1;
}

// ---------------------------------------------------------------------------
// Kernel 3: attn[b,i,j] = sum_d q[b,i,d]*k[b,j,d] from pre-converted bf16.
// r5 structure (32x512 tile, 4 waves, XOR-swizzled LDS staging) with ONE
// mechanism change: the epilogue streams FULL-LINE NONTEMPORAL stores in
// strictly row-sequential per-wave order (wave w owns rows w*8..w*8+7).
// NT bypasses L2 dirty-allocation so DRAM sees the program's sequential
// address order, not the hashed eviction order. grid = 4096 blocks.
// ---------------------------------------------------------------------------
__global__ __launch_bounds__(256) void attn_kernel(
    const unsigned short* __restrict__ qbf,
    const unsigned short* __restrict__ kbf,
    float* __restrict__ attn)
{
    __shared__ float lds[32 * 512];   // 64 KB, f32x4-swizzled

    int bid = blockIdx.x;
    // XCD-aware swizzle: 4096 % 8 == 0, contiguous 512-block chunk per XCD
    int swz = (bid & 7) * 512 + (bid >> 3);
    int b   = swz >> 10;
    int rem = swz & 1023;
    int ti  = rem >> 3;    // 0..127  (i-tile)
    int tj  = rem & 7;     // 0..7    (j-tile)

    int tid  = threadIdx.x;
    int wid  = tid >> 6;
    int lane = tid & 63;
    int i0 = ti * 32;
    int j0 = tj * 512;
    int jw = j0 + wid * 128;          // this wave's col base for compute

    const unsigned short* qb = qbf + (size_t)b * LL * DD;
    const unsigned short* kb = kbf + (size_t)b * LL * DD;

    int lr = lane & 15;               // fragment row within 16
    int g  = lane >> 4;               // 0..3
    int lk = g * 8;                   // k-octet base within 32

    f32x4 acc[2][8];
    #pragma unroll
    for (int m = 0; m < 2; m++)
        #pragma unroll
        for (int n = 0; n < 8; n++)
            acc[m][n] = (f32x4){0.f, 0.f, 0.f, 0.f};

    #pragma unroll
    for (int kk = 0; kk < 2; kk++) {
        int k0 = kk * 32 + lk;
        bf16x8 qf[2], kf[8];
        #pragma unroll
        for (int m = 0; m < 2; m++)
            qf[m] = *(const bf16x8*)(qb + (size_t)(i0 + m * 16 + lr) * DD + k0);
        #pragma unroll
        for (int n = 0; n < 8; n++)
            kf[n] = *(const bf16x8*)(kb + (size_t)(jw + n * 16 + lr) * DD + k0);
        // swapped operands: lane holds i = i0+m*16+(lane&15),
        // j = jw + n*16 + (lane>>4)*4 + reg  (4 consecutive j per lane)
        #pragma unroll
        for (int m = 0; m < 2; m++)
            #pragma unroll
            for (int n = 0; n < 8; n++)
                acc[m][n] = __builtin_amdgcn_mfma_f32_16x16x32_bf16(
                    kf[n], qf[m], acc[m][n], 0, 0, 0);
    }

    // stage tile in LDS: position (row, col4 ^ (row&7)) in f32x4 units
    f32x4* l4 = (f32x4*)lds;
    #pragma unroll
    for (int m = 0; m < 2; m++) {
        int row = m * 16 + lr;                     // 0..31
        #pragma unroll
        for (int n = 0; n < 8; n++) {
            int col4 = wid * 32 + n * 4 + g;       // 0..127
            l4[row * 128 + (col4 ^ (row & 7))] = acc[m][n];
        }
    }
    __syncthreads();

    // wave-sequential NT full-line store: wave w streams rows w*8..w*8+7,
    // each row as two 1KB contiguous wave-instructions (2KB runs).
    float* ab = attn + (size_t)b * LL * LL;
    #pragma unroll
    for (int r8 = 0; r8 < 8; r8++) {
        int row = wid * 8 + r8;
        #pragma unroll
        for (int h = 0; h < 2; h++) {
            int col4 = h * 64 + lane;              // 0..127
            f32x4 val = l4[row * 128 + (col4 ^ (row & 7))];
            __builtin_nontemporal_store(
                val, (f32x4*)(ab + (size_t)(i0 + row) * LL + j0 + col4 * 4));
        }
    }
}

extern "C" void kernel_launch(void* const* d_in, const int* in_sizes, int n_in,
                              void* d_out, int out_size, void* d_ws, size_t ws_size,
                              hipStream_t stream) {
    const float* q   = (const float*)d_in[0];
    const float* k   = (const float*)d_in[1];
    const float* v   = (const float*)d_in[2];
    const float* vec = (const float*)d_in[3];

    float* out  = (float*)d_out;                          // [4,4096,64]
    float* attn = out + (size_t)BB * LL * DD;             // [4,4096,4096]

    unsigned short* qbf = (unsigned short*)d_ws;          // 2 MB
    unsigned short* kbf = qbf + (size_t)BB * LL * DD;     // 2 MB
    float* part = (float*)(kbf + (size_t)BB * LL * DD);   // 512*64 f32 = 128 KB

    convert_kernel<<<1024, 256, 0, stream>>>(q, k, qbf, kbf, part);
    out_kernel<<<512, 256, 0, stream>>>(q, v, vec, part, out);
    attn_kernel<<<4096, 256, 0, stream>>>(qbf, kbf, attn);
}